// Round 1
// baseline (1564.656 us; speedup 1.0000x reference)
//
#include <hip/hip_runtime.h>
#include <math.h>

// GAT layer: xp = x@W; per-edge softmax over dst segments; aggregate; BN+ReLU+residual.
// Round 1 baseline: atomic-scatter aggregation (to be replaced by CSR gather if
// counters show it dominating).

constexpr float NEG_SLOPE = 0.2f;
constexpr float BN_EPS = 1e-5f;
constexpr float SM_EPS = 1e-16f;

// ---------------------------------------------------------------------------
// K1: xp = x @ W  (n x 128 @ 128 x 128), plus per-head attention dots
//     a_s[n][h] = sum_f xp[n][h*16+f]*att_src[h][f], same for a_d.
// Block: 256 threads, 32 rows/block. x tile staged in LDS (16KB); W read from
// global (64KB, L2-resident across all blocks). 4 rows x 4 cols per thread.
// ---------------------------------------------------------------------------
__global__ __launch_bounds__(256) void k_gemm(
    const float* __restrict__ x, const float* __restrict__ W,
    const float* __restrict__ att_src, const float* __restrict__ att_dst,
    float* __restrict__ xp, float* __restrict__ a_s, float* __restrict__ a_d,
    int n)
{
    __shared__ float Xl[32 * 128];
    const int tid = threadIdx.x;
    const int row0 = blockIdx.x * 32;

    // stage 32 rows of x (float4-coalesced)
    const float4* x4 = (const float4*)x;
    float4* Xl4 = (float4*)Xl;
#pragma unroll
    for (int i = 0; i < 4; ++i) {
        int idx = tid + i * 256;            // 1024 float4 total
        int r = row0 + (idx >> 5);          // 32 float4 per row
        Xl4[idx] = (r < n) ? x4[(size_t)r * 32 + (idx & 31)]
                           : make_float4(0.f, 0.f, 0.f, 0.f);
    }
    __syncthreads();

    const int tx = tid & 31;   // col4 index: cols tx*4 .. tx*4+3
    const int ty = tid >> 5;   // row group:  rows ty*4 .. ty*4+3

    float acc[4][4] = {};
    for (int k = 0; k < 128; k += 4) {
        float4 xv[4];
#pragma unroll
        for (int r = 0; r < 4; ++r)
            xv[r] = *(const float4*)&Xl[(ty * 4 + r) * 128 + k];
#pragma unroll
        for (int kk = 0; kk < 4; ++kk) {
            float4 wv = *(const float4*)&W[(size_t)(k + kk) * 128 + tx * 4];
#pragma unroll
            for (int r = 0; r < 4; ++r) {
                float xs = (&xv[r].x)[kk];
                acc[r][0] = fmaf(xs, wv.x, acc[r][0]);
                acc[r][1] = fmaf(xs, wv.y, acc[r][1]);
                acc[r][2] = fmaf(xs, wv.z, acc[r][2]);
                acc[r][3] = fmaf(xs, wv.w, acc[r][3]);
            }
        }
    }

    // write xp
#pragma unroll
    for (int r = 0; r < 4; ++r) {
        int row = row0 + ty * 4 + r;
        if (row < n) {
            *(float4*)&xp[(size_t)row * 128 + tx * 4] =
                make_float4(acc[r][0], acc[r][1], acc[r][2], acc[r][3]);
        }
    }

    // attention dots: head h = tx/4, f = (tx&3)*4 + j; reduce across quad lanes
    const int h = tx >> 2;
    const int fbase = (tx & 3) * 4;
    float asv[4], adv[4];
#pragma unroll
    for (int j = 0; j < 4; ++j) {
        asv[j] = att_src[h * 16 + fbase + j];
        adv[j] = att_dst[h * 16 + fbase + j];
    }
#pragma unroll
    for (int r = 0; r < 4; ++r) {
        float ps = acc[r][0] * asv[0] + acc[r][1] * asv[1] +
                   acc[r][2] * asv[2] + acc[r][3] * asv[3];
        float pd = acc[r][0] * adv[0] + acc[r][1] * adv[1] +
                   acc[r][2] * adv[2] + acc[r][3] * adv[3];
        ps += __shfl_xor(ps, 1); ps += __shfl_xor(ps, 2);
        pd += __shfl_xor(pd, 1); pd += __shfl_xor(pd, 2);
        if ((tx & 3) == 0) {
            int row = row0 + ty * 4 + r;
            if (row < n) {
                a_s[(size_t)row * 8 + h] = ps;
                a_d[(size_t)row * 8 + h] = pd;
            }
        }
    }
}

// ---------------------------------------------------------------------------
// K2: per-edge p = exp(leaky_relu(a_s[src]+a_d[dst])); store p; atomic sum
//     into ssum[dst][h]. Self-loops are edges [E, E+n).
//     (Segment-max skipped: alpha is invariant to the shift; logits O(10).)
// ---------------------------------------------------------------------------
__global__ __launch_bounds__(256) void k_edge1(
    const int* __restrict__ ei, int E, int n,
    const float* __restrict__ a_s, const float* __restrict__ a_d,
    float* __restrict__ pbuf, float* __restrict__ ssum)
{
    int e = blockIdx.x * 256 + threadIdx.x;
    int tot = E + n;
    if (e >= tot) return;
    int src, dst;
    if (e < E) { src = ei[e]; dst = ei[E + e]; }
    else       { src = dst = e - E; }

    const float4* as4 = (const float4*)(a_s + (size_t)src * 8);
    const float4* ad4 = (const float4*)(a_d + (size_t)dst * 8);
    float4 s0 = as4[0], s1 = as4[1];
    float4 d0 = ad4[0], d1 = ad4[1];
    float ev[8] = { s0.x + d0.x, s0.y + d0.y, s0.z + d0.z, s0.w + d0.w,
                    s1.x + d1.x, s1.y + d1.y, s1.z + d1.z, s1.w + d1.w };
    float p[8];
#pragma unroll
    for (int h = 0; h < 8; ++h) {
        float v = ev[h];
        v = v > 0.f ? v : NEG_SLOPE * v;
        p[h] = __expf(v);
    }
    float* pb = pbuf + (size_t)e * 8;
    *(float4*)(pb + 0) = make_float4(p[0], p[1], p[2], p[3]);
    *(float4*)(pb + 4) = make_float4(p[4], p[5], p[6], p[7]);

    float* sd = ssum + (size_t)dst * 8;
#pragma unroll
    for (int h = 0; h < 8; ++h) atomicAdd(sd + h, p[h]);
}

// ---------------------------------------------------------------------------
// K3: scatter messages: agg[dst][c] += alpha_eh * xp[src][c].
//     32 threads per edge, one float4 (4 channels) per thread.
// ---------------------------------------------------------------------------
__global__ __launch_bounds__(256) void k_edge2(
    const int* __restrict__ ei, int E, int n,
    const float* __restrict__ xp, const float* __restrict__ pbuf,
    const float* __restrict__ ssum, float* __restrict__ agg)
{
    long long t = (long long)blockIdx.x * 256 + threadIdx.x;
    int e = (int)(t >> 5);
    int lane = (int)(t & 31);
    int tot = E + n;
    if (e >= tot) return;
    int src, dst;
    if (e < E) { src = ei[e]; dst = ei[E + e]; }
    else       { src = dst = e - E; }

    int h = lane >> 2;  // c = lane*4 .. lane*4+3, all in head (lane*4)/16
    float alpha = pbuf[(size_t)e * 8 + h] / (ssum[(size_t)dst * 8 + h] + SM_EPS);
    float4 v = *(const float4*)&xp[(size_t)src * 128 + lane * 4];
    float* ag = &agg[(size_t)dst * 128 + lane * 4];
    atomicAdd(ag + 0, alpha * v.x);
    atomicAdd(ag + 1, alpha * v.y);
    atomicAdd(ag + 2, alpha * v.z);
    atomicAdd(ag + 3, alpha * v.w);
}

// ---------------------------------------------------------------------------
// K4: per-channel sum and sum-of-squares of h = agg + bias (for BN stats).
// ---------------------------------------------------------------------------
__global__ __launch_bounds__(256) void k_bnstats(
    const float* __restrict__ agg, const float* __restrict__ bias, int n,
    float* __restrict__ stats)
{
    int c = threadIdx.x & 127;
    int half = threadIdx.x >> 7;  // 0..1
    float b = bias[c];
    float s = 0.f, s2 = 0.f;
    for (int r = blockIdx.x * 2 + half; r < n; r += gridDim.x * 2) {
        float v = agg[(size_t)r * 128 + c] + b;
        s += v;
        s2 += v * v;
    }
    atomicAdd(&stats[c], s);
    atomicAdd(&stats[128 + c], s2);
}

// ---------------------------------------------------------------------------
// K5: finalize: BN (batch stats, biased var) + ReLU + residual.
// ---------------------------------------------------------------------------
__global__ __launch_bounds__(256) void k_final(
    const float* __restrict__ agg, const float* __restrict__ bias,
    const float* __restrict__ gamma, const float* __restrict__ beta,
    const float* __restrict__ stats, const float* __restrict__ x,
    float* __restrict__ out, int n)
{
    int i = blockIdx.x * 256 + threadIdx.x;
    int total = n * 128;
    if (i >= total) return;
    int c = i & 127;
    float invn = 1.0f / (float)n;
    float mean = stats[c] * invn;
    float var = stats[128 + c] * invn - mean * mean;
    float v = agg[i] + bias[c];
    v = (v - mean) * rsqrtf(var + BN_EPS) * gamma[c] + beta[c];
    v = fmaxf(v, 0.f);
    out[i] = v + x[i];
}

// ---------------------------------------------------------------------------
extern "C" void kernel_launch(void* const* d_in, const int* in_sizes, int n_in,
                              void* d_out, int out_size, void* d_ws, size_t ws_size,
                              hipStream_t stream)
{
    const float* x        = (const float*)d_in[0];
    const int*   ei       = (const int*)d_in[1];
    const float* W        = (const float*)d_in[2];
    const float* att_src  = (const float*)d_in[3];
    const float* att_dst  = (const float*)d_in[4];
    const float* bias     = (const float*)d_in[5];
    const float* bn_gamma = (const float*)d_in[6];
    const float* bn_beta  = (const float*)d_in[7];
    float* out = (float*)d_out;

    const int n = in_sizes[0] / 128;
    const int E = in_sizes[1] / 2;
    const int tot = E + n;

    // workspace layout (floats)
    float* xp    = (float*)d_ws;
    float* a_s   = xp + (size_t)n * 128;
    float* a_d   = a_s + (size_t)n * 8;
    float* ssum  = a_d + (size_t)n * 8;
    float* pbuf  = ssum + (size_t)n * 8;
    float* agg   = pbuf + (size_t)tot * 8;
    float* stats = agg + (size_t)n * 128;

    // zero accumulators (ws is poisoned 0xAA before every launch)
    hipMemsetAsync(ssum, 0, (size_t)n * 8 * sizeof(float), stream);
    hipMemsetAsync(agg, 0, (size_t)n * 128 * sizeof(float), stream);
    hipMemsetAsync(stats, 0, 256 * sizeof(float), stream);

    // K1: GEMM + attention dots
    k_gemm<<<(n + 31) / 32, 256, 0, stream>>>(x, W, att_src, att_dst, xp, a_s, a_d, n);

    // K2: edge logits -> p, denominator sums
    k_edge1<<<(tot + 255) / 256, 256, 0, stream>>>(ei, E, n, a_s, a_d, pbuf, ssum);

    // K3: scatter-aggregate messages
    long long t3 = (long long)tot * 32;
    k_edge2<<<(int)((t3 + 255) / 256), 256, 0, stream>>>(ei, E, n, xp, pbuf, ssum, agg);

    // K4: BN stats
    k_bnstats<<<320, 256, 0, stream>>>(agg, bias, n, stats);

    // K5: finalize
    k_final<<<(n * 128 + 255) / 256, 256, 0, stream>>>(agg, bias, bn_gamma, bn_beta,
                                                       stats, x, out, n);
}

// Round 2
// 391.235 us; speedup vs baseline: 3.9993x; 3.9993x over previous
//
#include <hip/hip_runtime.h>
#include <math.h>

// GAT layer, R2: CSR-gather aggregation (no float atomics on the hot path).
// Pipeline: gemm+att-dots -> degree count -> scan -> bucket -> gather -> BN.

constexpr float NEG_SLOPE = 0.2f;
constexpr float BN_EPS = 1e-5f;
constexpr float SM_EPS = 1e-16f;

// ---------------------------------------------------------------------------
// K1: xp = x @ W  (n x 128 @ 128 x 128), plus per-head attention dots.
// ---------------------------------------------------------------------------
__global__ __launch_bounds__(256) void k_gemm(
    const float* __restrict__ x, const float* __restrict__ W,
    const float* __restrict__ att_src, const float* __restrict__ att_dst,
    float* __restrict__ xp, float* __restrict__ a_s, float* __restrict__ a_d,
    int n)
{
    __shared__ float Xl[32 * 128];
    const int tid = threadIdx.x;
    const int row0 = blockIdx.x * 32;

    const float4* x4 = (const float4*)x;
    float4* Xl4 = (float4*)Xl;
#pragma unroll
    for (int i = 0; i < 4; ++i) {
        int idx = tid + i * 256;
        int r = row0 + (idx >> 5);
        Xl4[idx] = (r < n) ? x4[(size_t)r * 32 + (idx & 31)]
                           : make_float4(0.f, 0.f, 0.f, 0.f);
    }
    __syncthreads();

    const int tx = tid & 31;
    const int ty = tid >> 5;

    float acc[4][4] = {};
    for (int k = 0; k < 128; k += 4) {
        float4 xv[4];
#pragma unroll
        for (int r = 0; r < 4; ++r)
            xv[r] = *(const float4*)&Xl[(ty * 4 + r) * 128 + k];
#pragma unroll
        for (int kk = 0; kk < 4; ++kk) {
            float4 wv = *(const float4*)&W[(size_t)(k + kk) * 128 + tx * 4];
#pragma unroll
            for (int r = 0; r < 4; ++r) {
                float xs = (&xv[r].x)[kk];
                acc[r][0] = fmaf(xs, wv.x, acc[r][0]);
                acc[r][1] = fmaf(xs, wv.y, acc[r][1]);
                acc[r][2] = fmaf(xs, wv.z, acc[r][2]);
                acc[r][3] = fmaf(xs, wv.w, acc[r][3]);
            }
        }
    }

#pragma unroll
    for (int r = 0; r < 4; ++r) {
        int row = row0 + ty * 4 + r;
        if (row < n) {
            *(float4*)&xp[(size_t)row * 128 + tx * 4] =
                make_float4(acc[r][0], acc[r][1], acc[r][2], acc[r][3]);
        }
    }

    const int h = tx >> 2;
    const int fbase = (tx & 3) * 4;
    float asv[4], adv[4];
#pragma unroll
    for (int j = 0; j < 4; ++j) {
        asv[j] = att_src[h * 16 + fbase + j];
        adv[j] = att_dst[h * 16 + fbase + j];
    }
#pragma unroll
    for (int r = 0; r < 4; ++r) {
        float ps = acc[r][0] * asv[0] + acc[r][1] * asv[1] +
                   acc[r][2] * asv[2] + acc[r][3] * asv[3];
        float pd = acc[r][0] * adv[0] + acc[r][1] * adv[1] +
                   acc[r][2] * adv[2] + acc[r][3] * adv[3];
        ps += __shfl_xor(ps, 1); ps += __shfl_xor(ps, 2);
        pd += __shfl_xor(pd, 1); pd += __shfl_xor(pd, 2);
        if ((tx & 3) == 0) {
            int row = row0 + ty * 4 + r;
            if (row < n) {
                a_s[(size_t)row * 8 + h] = ps;
                a_d[(size_t)row * 8 + h] = pd;
            }
        }
    }
}

// ---------------------------------------------------------------------------
// K2: degree histogram over dst (self-loops are edges [E, E+n)).
// ---------------------------------------------------------------------------
__global__ __launch_bounds__(256) void k_count(
    const int* __restrict__ ei, int E, int n, int* __restrict__ deg)
{
    int e = blockIdx.x * 256 + threadIdx.x;
    if (e >= E + n) return;
    int dst = (e < E) ? ei[E + e] : (e - E);
    atomicAdd(&deg[dst], 1);
}

// ---------------------------------------------------------------------------
// K3: exclusive scan of deg -> row_ptr[0..n]. Single block, 1024 threads,
// 8 elements/thread/chunk (chunk = 8192), Hillis-Steele block scan of partials.
// ---------------------------------------------------------------------------
__global__ __launch_bounds__(1024) void k_scan(
    const int* __restrict__ deg, int* __restrict__ row_ptr, int n)
{
    __shared__ int lds[1024];
    __shared__ int s_carry;
    const int tid = threadIdx.x;
    if (tid == 0) { s_carry = 0; row_ptr[0] = 0; }
    __syncthreads();

    for (int base = 0; base < n; base += 8192) {
        int v[8]; int sum = 0;
#pragma unroll
        for (int j = 0; j < 8; ++j) {
            int i = base + tid * 8 + j;
            v[j] = (i < n) ? deg[i] : 0;
            sum += v[j];
        }
        lds[tid] = sum;
        __syncthreads();
        for (int off = 1; off < 1024; off <<= 1) {
            int t = (tid >= off) ? lds[tid - off] : 0;
            __syncthreads();
            if (tid >= off) lds[tid] += t;
            __syncthreads();
        }
        int total = lds[1023];
        int run = (tid == 0 ? 0 : lds[tid - 1]) + s_carry;
#pragma unroll
        for (int j = 0; j < 8; ++j) {
            int i = base + tid * 8 + j;
            run += v[j];
            if (i < n) row_ptr[i + 1] = run;
        }
        __syncthreads();
        if (tid == 0) s_carry += total;
        __syncthreads();
    }
}

// ---------------------------------------------------------------------------
// K4: bucket edges into CSR slots (store src only; p recomputed in gather).
// ---------------------------------------------------------------------------
__global__ __launch_bounds__(256) void k_bucket(
    const int* __restrict__ ei, int E, int n,
    const int* __restrict__ row_ptr, int* __restrict__ cursor,
    int* __restrict__ csr_src)
{
    int e = blockIdx.x * 256 + threadIdx.x;
    if (e >= E + n) return;
    int src, dst;
    if (e < E) { src = ei[e]; dst = ei[E + e]; }
    else       { src = dst = e - E; }
    int slot = row_ptr[dst] + atomicAdd(&cursor[dst], 1);
    csr_src[slot] = src;
}

// ---------------------------------------------------------------------------
// K5: per-dst gather-aggregate. 128 threads per node (channel c), 2 nodes
// per block. Single pass: acc = sum p*xp[src][c], s = sum p; out = acc/(s+eps).
// xp row read is 512B fully coalesced per edge.
// ---------------------------------------------------------------------------
__global__ __launch_bounds__(256) void k_gather(
    const int* __restrict__ row_ptr, const int* __restrict__ csr_src,
    const float* __restrict__ a_s, const float* __restrict__ a_d,
    const float* __restrict__ xp, float* __restrict__ agg, int n)
{
    int node = blockIdx.x * 2 + (threadIdx.x >> 7);
    if (node >= n) return;
    int c = threadIdx.x & 127;
    int h = c >> 4;
    float ad = a_d[(size_t)node * 8 + h];
    int beg = row_ptr[node], end = row_ptr[node + 1];
    float acc = 0.f, s = 0.f;
    for (int slot = beg; slot < end; ++slot) {
        int src = csr_src[slot];
        float v = a_s[(size_t)src * 8 + h] + ad;
        v = v > 0.f ? v : NEG_SLOPE * v;
        float p = __expf(v);
        s += p;
        acc = fmaf(p, xp[(size_t)src * 128 + c], acc);
    }
    agg[(size_t)node * 128 + c] = acc / (s + SM_EPS);
}

// ---------------------------------------------------------------------------
// K6: per-channel sum / sum-of-squares of h = agg + bias (BN stats).
// ---------------------------------------------------------------------------
__global__ __launch_bounds__(256) void k_bnstats(
    const float* __restrict__ agg, const float* __restrict__ bias, int n,
    float* __restrict__ stats)
{
    int c = threadIdx.x & 127;
    int half = threadIdx.x >> 7;
    float b = bias[c];
    float s = 0.f, s2 = 0.f;
    for (int r = blockIdx.x * 2 + half; r < n; r += gridDim.x * 2) {
        float v = agg[(size_t)r * 128 + c] + b;
        s += v;
        s2 += v * v;
    }
    atomicAdd(&stats[c], s);
    atomicAdd(&stats[128 + c], s2);
}

// ---------------------------------------------------------------------------
// K7: finalize: BN (batch stats, biased var) + ReLU + residual.
// ---------------------------------------------------------------------------
__global__ __launch_bounds__(256) void k_final(
    const float* __restrict__ agg, const float* __restrict__ bias,
    const float* __restrict__ gamma, const float* __restrict__ beta,
    const float* __restrict__ stats, const float* __restrict__ x,
    float* __restrict__ out, int n)
{
    int i = blockIdx.x * 256 + threadIdx.x;
    int total = n * 128;
    if (i >= total) return;
    int c = i & 127;
    float invn = 1.0f / (float)n;
    float mean = stats[c] * invn;
    float var = stats[128 + c] * invn - mean * mean;
    float v = agg[i] + bias[c];
    v = (v - mean) * rsqrtf(var + BN_EPS) * gamma[c] + beta[c];
    v = fmaxf(v, 0.f);
    out[i] = v + x[i];
}

// ---------------------------------------------------------------------------
extern "C" void kernel_launch(void* const* d_in, const int* in_sizes, int n_in,
                              void* d_out, int out_size, void* d_ws, size_t ws_size,
                              hipStream_t stream)
{
    const float* x        = (const float*)d_in[0];
    const int*   ei       = (const int*)d_in[1];
    const float* W        = (const float*)d_in[2];
    const float* att_src  = (const float*)d_in[3];
    const float* att_dst  = (const float*)d_in[4];
    const float* bias     = (const float*)d_in[5];
    const float* bn_gamma = (const float*)d_in[6];
    const float* bn_beta  = (const float*)d_in[7];
    float* out = (float*)d_out;

    const int n = in_sizes[0] / 128;
    const int E = in_sizes[1] / 2;
    const int tot = E + n;

    // workspace layout
    float* xp      = (float*)d_ws;               // n*128
    float* a_s     = xp + (size_t)n * 128;       // n*8
    float* a_d     = a_s + (size_t)n * 8;        // n*8
    float* agg     = a_d + (size_t)n * 8;        // n*128
    float* stats   = agg + (size_t)n * 128;      // 256
    int*   deg     = (int*)(stats + 256);        // n
    int*   row_ptr = deg + n;                    // n+1
    int*   cursor  = row_ptr + n + 1;            // n
    int*   csr_src = cursor + n;                 // E+n

    hipMemsetAsync(deg, 0, (size_t)n * sizeof(int), stream);
    hipMemsetAsync(cursor, 0, (size_t)n * sizeof(int), stream);
    hipMemsetAsync(stats, 0, 256 * sizeof(float), stream);

    k_gemm<<<(n + 31) / 32, 256, 0, stream>>>(x, W, att_src, att_dst, xp, a_s, a_d, n);
    k_count<<<(tot + 255) / 256, 256, 0, stream>>>(ei, E, n, deg);
    k_scan<<<1, 1024, 0, stream>>>(deg, row_ptr, n);
    k_bucket<<<(tot + 255) / 256, 256, 0, stream>>>(ei, E, n, row_ptr, cursor, csr_src);
    k_gather<<<(n + 1) / 2, 256, 0, stream>>>(row_ptr, csr_src, a_s, a_d, xp, agg, n);
    k_bnstats<<<320, 256, 0, stream>>>(agg, bias, n, stats);
    k_final<<<(n * 128 + 255) / 256, 256, 0, stream>>>(agg, bias, bn_gamma, bn_beta,
                                                       stats, x, out, n);
}

// Round 3
// 351.953 us; speedup vs baseline: 4.4456x; 1.1116x over previous
//
#include <hip/hip_runtime.h>
#include <math.h>

// GAT layer, R3: bf16 message gather (halved gathered bytes), fast wave-scan,
// single-atomic bucket. Pipeline: gemm(+bf16 xp, att dots) -> count -> scan
// (fused cursor init) -> bucket -> gather(bf16) -> bnstats -> final.

constexpr float NEG_SLOPE = 0.2f;
constexpr float BN_EPS = 1e-5f;
constexpr float SM_EPS = 1e-16f;

__device__ inline unsigned bf16rne(float f) {
    unsigned b = __float_as_uint(f);
    return (b + 0x7fffu + ((b >> 16) & 1u)) >> 16;
}

// ---------------------------------------------------------------------------
// K1: xp = x @ W (n x 128 @ 128 x 128) -> bf16, plus per-head attention dots.
// ---------------------------------------------------------------------------
__global__ __launch_bounds__(256) void k_gemm(
    const float* __restrict__ x, const float* __restrict__ W,
    const float* __restrict__ att_src, const float* __restrict__ att_dst,
    unsigned* __restrict__ xpb,   // n*64 uints = n*128 bf16
    float* __restrict__ a_s, float* __restrict__ a_d, int n)
{
    __shared__ float Xl[32 * 128];
    const int tid = threadIdx.x;
    const int row0 = blockIdx.x * 32;

    const float4* x4 = (const float4*)x;
    float4* Xl4 = (float4*)Xl;
#pragma unroll
    for (int i = 0; i < 4; ++i) {
        int idx = tid + i * 256;
        int r = row0 + (idx >> 5);
        Xl4[idx] = (r < n) ? x4[(size_t)r * 32 + (idx & 31)]
                           : make_float4(0.f, 0.f, 0.f, 0.f);
    }
    __syncthreads();

    const int tx = tid & 31;
    const int ty = tid >> 5;

    float acc[4][4] = {};
    for (int k = 0; k < 128; k += 4) {
        float4 xv[4];
#pragma unroll
        for (int r = 0; r < 4; ++r)
            xv[r] = *(const float4*)&Xl[(ty * 4 + r) * 128 + k];
#pragma unroll
        for (int kk = 0; kk < 4; ++kk) {
            float4 wv = *(const float4*)&W[(size_t)(k + kk) * 128 + tx * 4];
#pragma unroll
            for (int r = 0; r < 4; ++r) {
                float xs = (&xv[r].x)[kk];
                acc[r][0] = fmaf(xs, wv.x, acc[r][0]);
                acc[r][1] = fmaf(xs, wv.y, acc[r][1]);
                acc[r][2] = fmaf(xs, wv.z, acc[r][2]);
                acc[r][3] = fmaf(xs, wv.w, acc[r][3]);
            }
        }
    }

    // write bf16 xp: 4 values -> uint2 (8B)
#pragma unroll
    for (int r = 0; r < 4; ++r) {
        int row = row0 + ty * 4 + r;
        if (row < n) {
            uint2 u;
            u.x = bf16rne(acc[r][0]) | (bf16rne(acc[r][1]) << 16);
            u.y = bf16rne(acc[r][2]) | (bf16rne(acc[r][3]) << 16);
            *(uint2*)&xpb[(size_t)row * 64 + tx * 2] = u;
        }
    }

    const int h = tx >> 2;
    const int fbase = (tx & 3) * 4;
    float asv[4], adv[4];
#pragma unroll
    for (int j = 0; j < 4; ++j) {
        asv[j] = att_src[h * 16 + fbase + j];
        adv[j] = att_dst[h * 16 + fbase + j];
    }
#pragma unroll
    for (int r = 0; r < 4; ++r) {
        float ps = acc[r][0] * asv[0] + acc[r][1] * asv[1] +
                   acc[r][2] * asv[2] + acc[r][3] * asv[3];
        float pd = acc[r][0] * adv[0] + acc[r][1] * adv[1] +
                   acc[r][2] * adv[2] + acc[r][3] * adv[3];
        ps += __shfl_xor(ps, 1); ps += __shfl_xor(ps, 2);
        pd += __shfl_xor(pd, 1); pd += __shfl_xor(pd, 2);
        if ((tx & 3) == 0) {
            int row = row0 + ty * 4 + r;
            if (row < n) {
                a_s[(size_t)row * 8 + h] = ps;
                a_d[(size_t)row * 8 + h] = pd;
            }
        }
    }
}

// ---------------------------------------------------------------------------
// K2: degree histogram over dst (self-loops are edges [E, E+n)).
// ---------------------------------------------------------------------------
__global__ __launch_bounds__(256) void k_count(
    const int* __restrict__ ei, int E, int n, int* __restrict__ deg)
{
    int e = blockIdx.x * 256 + threadIdx.x;
    if (e >= E + n) return;
    int dst = (e < E) ? ei[E + e] : (e - E);
    atomicAdd(&deg[dst], 1);
}

// ---------------------------------------------------------------------------
// K3: exclusive scan of deg -> row_ptr[0..n]; also cursor[i] = row_ptr[i].
// Single block, 1024 threads, ELT=40 contiguous elems/thread, wave scan via
// __shfl_up + one LDS pass over the 16 wave sums (~3 barriers total).
// ---------------------------------------------------------------------------
__global__ __launch_bounds__(1024) void k_scan(
    const int* __restrict__ deg, int* __restrict__ row_ptr,
    int* __restrict__ cursor, int n)
{
    constexpr int ELT = 40;  // 1024*40 = 40960 >= n
    __shared__ int wsum[16];
    const int tid = threadIdx.x;
    const int lane = tid & 63;
    const int wid = tid >> 6;

    int v[ELT];
    int sum = 0;
    const int base = tid * ELT;
#pragma unroll
    for (int j = 0; j < ELT; ++j) {
        int i = base + j;
        v[j] = (i < n) ? deg[i] : 0;
        sum += v[j];
    }

    // inclusive wave scan of per-thread sums
    int inc = sum;
#pragma unroll
    for (int off = 1; off < 64; off <<= 1) {
        int t = __shfl_up(inc, off);
        if (lane >= off) inc += t;
    }
    if (lane == 63) wsum[wid] = inc;
    __syncthreads();
    if (wid == 0) {
        int w = (lane < 16) ? wsum[lane] : 0;
        int wi = w;
#pragma unroll
        for (int off = 1; off < 16; off <<= 1) {
            int t = __shfl_up(wi, off);
            if (lane >= off) wi += t;
        }
        if (lane < 16) wsum[lane] = wi - w;  // exclusive wave offsets
    }
    __syncthreads();

    int run = wsum[wid] + (inc - sum);  // exclusive prefix for this thread
    if (tid == 0) row_ptr[0] = 0;
#pragma unroll
    for (int j = 0; j < ELT; ++j) {
        int i = base + j;
        if (i < n) {
            cursor[i] = run;             // = row_ptr[i]
            run += v[j];
            row_ptr[i + 1] = run;
        }
    }
}

// ---------------------------------------------------------------------------
// K4: bucket edges into CSR slots: slot = atomicAdd(&cursor[dst], 1).
// ---------------------------------------------------------------------------
__global__ __launch_bounds__(256) void k_bucket(
    const int* __restrict__ ei, int E, int n,
    int* __restrict__ cursor, int* __restrict__ csr_src)
{
    int e = blockIdx.x * 256 + threadIdx.x;
    if (e >= E + n) return;
    int src, dst;
    if (e < E) { src = ei[e]; dst = ei[E + e]; }
    else       { src = dst = e - E; }
    int slot = atomicAdd(&cursor[dst], 1);
    csr_src[slot] = src;
}

// ---------------------------------------------------------------------------
// K5: per-dst gather-aggregate, bf16 messages. 64 threads/node (2 channels
// each via bf16x2), 4 nodes/block. acc = sum p*xp[src][c]; out = acc/(s+eps).
// ---------------------------------------------------------------------------
__global__ __launch_bounds__(256) void k_gather(
    const int* __restrict__ row_ptr, const int* __restrict__ csr_src,
    const float* __restrict__ a_s, const float* __restrict__ a_d,
    const unsigned* __restrict__ xpb, float* __restrict__ agg, int n)
{
    int node = blockIdx.x * 4 + (threadIdx.x >> 6);
    if (node >= n) return;
    int lane = threadIdx.x & 63;     // channel pair: c = 2*lane, 2*lane+1
    int h = lane >> 3;               // (2*lane)>>4
    float ad = a_d[(size_t)node * 8 + h];
    int beg = row_ptr[node], end = row_ptr[node + 1];
    float acc0 = 0.f, acc1 = 0.f, s = 0.f;
    for (int slot = beg; slot < end; ++slot) {
        int src = csr_src[slot];
        float v = a_s[(size_t)src * 8 + h] + ad;
        v = v > 0.f ? v : NEG_SLOPE * v;
        float p = __expf(v);
        s += p;
        unsigned u = xpb[(size_t)src * 64 + lane];
        float f0 = __uint_as_float(u << 16);
        float f1 = __uint_as_float(u & 0xffff0000u);
        acc0 = fmaf(p, f0, acc0);
        acc1 = fmaf(p, f1, acc1);
    }
    float inv = 1.0f / (s + SM_EPS);
    *(float2*)&agg[(size_t)node * 128 + lane * 2] = make_float2(acc0 * inv, acc1 * inv);
}

// ---------------------------------------------------------------------------
// K6: per-channel sum / sum-of-squares of h = agg + bias (BN stats).
// ---------------------------------------------------------------------------
__global__ __launch_bounds__(256) void k_bnstats(
    const float* __restrict__ agg, const float* __restrict__ bias, int n,
    float* __restrict__ stats)
{
    int c = threadIdx.x & 127;
    int half = threadIdx.x >> 7;
    float b = bias[c];
    float s = 0.f, s2 = 0.f;
    for (int r = blockIdx.x * 2 + half; r < n; r += gridDim.x * 2) {
        float v = agg[(size_t)r * 128 + c] + b;
        s += v;
        s2 += v * v;
    }
    atomicAdd(&stats[c], s);
    atomicAdd(&stats[128 + c], s2);
}

// ---------------------------------------------------------------------------
// K7: finalize: BN (batch stats, biased var) + ReLU + residual.
// ---------------------------------------------------------------------------
__global__ __launch_bounds__(256) void k_final(
    const float* __restrict__ agg, const float* __restrict__ bias,
    const float* __restrict__ gamma, const float* __restrict__ beta,
    const float* __restrict__ stats, const float* __restrict__ x,
    float* __restrict__ out, int n)
{
    int i = blockIdx.x * 256 + threadIdx.x;
    int total = n * 128;
    if (i >= total) return;
    int c = i & 127;
    float invn = 1.0f / (float)n;
    float mean = stats[c] * invn;
    float var = stats[128 + c] * invn - mean * mean;
    float v = agg[i] + bias[c];
    v = (v - mean) * rsqrtf(var + BN_EPS) * gamma[c] + beta[c];
    v = fmaxf(v, 0.f);
    out[i] = v + x[i];
}

// ---------------------------------------------------------------------------
extern "C" void kernel_launch(void* const* d_in, const int* in_sizes, int n_in,
                              void* d_out, int out_size, void* d_ws, size_t ws_size,
                              hipStream_t stream)
{
    const float* x        = (const float*)d_in[0];
    const int*   ei       = (const int*)d_in[1];
    const float* W        = (const float*)d_in[2];
    const float* att_src  = (const float*)d_in[3];
    const float* att_dst  = (const float*)d_in[4];
    const float* bias     = (const float*)d_in[5];
    const float* bn_gamma = (const float*)d_in[6];
    const float* bn_beta  = (const float*)d_in[7];
    float* out = (float*)d_out;

    const int n = in_sizes[0] / 128;
    const int E = in_sizes[1] / 2;
    const int tot = E + n;

    // workspace layout
    float*    agg     = (float*)d_ws;                  // n*128
    float*    a_s     = agg + (size_t)n * 128;         // n*8
    float*    a_d     = a_s + (size_t)n * 8;           // n*8
    float*    stats   = a_d + (size_t)n * 8;           // 256
    unsigned* xpb     = (unsigned*)(stats + 256);      // n*64 (bf16 x2)
    int*      deg     = (int*)(xpb + (size_t)n * 64);  // n
    int*      row_ptr = deg + n;                       // n+1
    int*      cursor  = row_ptr + n + 1;               // n
    int*      csr_src = cursor + n;                    // E+n

    hipMemsetAsync(deg, 0, (size_t)n * sizeof(int), stream);
    hipMemsetAsync(stats, 0, 256 * sizeof(float), stream);

    k_gemm<<<(n + 31) / 32, 256, 0, stream>>>(x, W, att_src, att_dst, xpb, a_s, a_d, n);
    k_count<<<(tot + 255) / 256, 256, 0, stream>>>(ei, E, n, deg);
    k_scan<<<1, 1024, 0, stream>>>(deg, row_ptr, cursor, n);
    k_bucket<<<(tot + 255) / 256, 256, 0, stream>>>(ei, E, n, cursor, csr_src);
    k_gather<<<(n + 3) / 4, 256, 0, stream>>>(row_ptr, csr_src, a_s, a_d, xpb, agg, n);
    k_bnstats<<<320, 256, 0, stream>>>(agg, bias, n, stats);
    k_final<<<(n * 128 + 255) / 256, 256, 0, stream>>>(agg, bias, bn_gamma, bn_beta,
                                                       stats, x, out, n);
}

// Round 4
// 313.791 us; speedup vs baseline: 4.9863x; 1.1216x over previous
//
#include <hip/hip_runtime.h>
#include <math.h>

// GAT layer, R4: 4-way unrolled gather (MLP), degree-count fused into gemm,
// single memset. Pipeline: memset -> gemm(+count) -> scan -> bucket ->
// gather -> bnstats -> final.

constexpr float NEG_SLOPE = 0.2f;
constexpr float BN_EPS = 1e-5f;
constexpr float SM_EPS = 1e-16f;

__device__ inline unsigned bf16rne(float f) {
    unsigned b = __float_as_uint(f);
    return (b + 0x7fffu + ((b >> 16) & 1u)) >> 16;
}

// ---------------------------------------------------------------------------
// K1: degree histogram (grid-stride, hidden under FMA work) + xp = x@W -> bf16
//     + per-head attention dots.
// ---------------------------------------------------------------------------
__global__ __launch_bounds__(256) void k_gemm(
    const float* __restrict__ x, const float* __restrict__ W,
    const float* __restrict__ att_src, const float* __restrict__ att_dst,
    const int* __restrict__ ei, int E,
    unsigned* __restrict__ xpb, float* __restrict__ a_s, float* __restrict__ a_d,
    int* __restrict__ deg, int n)
{
    // fused degree count over E+n edges (self-loops are [E, E+n))
    {
        int tot = E + n;
        int stride = gridDim.x * 256;
        for (int e = blockIdx.x * 256 + threadIdx.x; e < tot; e += stride) {
            int dst = (e < E) ? ei[E + e] : (e - E);
            atomicAdd(&deg[dst], 1);
        }
    }

    __shared__ float Xl[32 * 128];
    const int tid = threadIdx.x;
    const int row0 = blockIdx.x * 32;

    const float4* x4 = (const float4*)x;
    float4* Xl4 = (float4*)Xl;
#pragma unroll
    for (int i = 0; i < 4; ++i) {
        int idx = tid + i * 256;
        int r = row0 + (idx >> 5);
        Xl4[idx] = (r < n) ? x4[(size_t)r * 32 + (idx & 31)]
                           : make_float4(0.f, 0.f, 0.f, 0.f);
    }
    __syncthreads();

    const int tx = tid & 31;
    const int ty = tid >> 5;

    float acc[4][4] = {};
    for (int k = 0; k < 128; k += 4) {
        float4 xv[4];
#pragma unroll
        for (int r = 0; r < 4; ++r)
            xv[r] = *(const float4*)&Xl[(ty * 4 + r) * 128 + k];
#pragma unroll
        for (int kk = 0; kk < 4; ++kk) {
            float4 wv = *(const float4*)&W[(size_t)(k + kk) * 128 + tx * 4];
#pragma unroll
            for (int r = 0; r < 4; ++r) {
                float xs = (&xv[r].x)[kk];
                acc[r][0] = fmaf(xs, wv.x, acc[r][0]);
                acc[r][1] = fmaf(xs, wv.y, acc[r][1]);
                acc[r][2] = fmaf(xs, wv.z, acc[r][2]);
                acc[r][3] = fmaf(xs, wv.w, acc[r][3]);
            }
        }
    }

#pragma unroll
    for (int r = 0; r < 4; ++r) {
        int row = row0 + ty * 4 + r;
        if (row < n) {
            uint2 u;
            u.x = bf16rne(acc[r][0]) | (bf16rne(acc[r][1]) << 16);
            u.y = bf16rne(acc[r][2]) | (bf16rne(acc[r][3]) << 16);
            *(uint2*)&xpb[(size_t)row * 64 + tx * 2] = u;
        }
    }

    const int h = tx >> 2;
    const int fbase = (tx & 3) * 4;
    float asv[4], adv[4];
#pragma unroll
    for (int j = 0; j < 4; ++j) {
        asv[j] = att_src[h * 16 + fbase + j];
        adv[j] = att_dst[h * 16 + fbase + j];
    }
#pragma unroll
    for (int r = 0; r < 4; ++r) {
        float ps = acc[r][0] * asv[0] + acc[r][1] * asv[1] +
                   acc[r][2] * asv[2] + acc[r][3] * asv[3];
        float pd = acc[r][0] * adv[0] + acc[r][1] * adv[1] +
                   acc[r][2] * adv[2] + acc[r][3] * adv[3];
        ps += __shfl_xor(ps, 1); ps += __shfl_xor(ps, 2);
        pd += __shfl_xor(pd, 1); pd += __shfl_xor(pd, 2);
        if ((tx & 3) == 0) {
            int row = row0 + ty * 4 + r;
            if (row < n) {
                a_s[(size_t)row * 8 + h] = ps;
                a_d[(size_t)row * 8 + h] = pd;
            }
        }
    }
}

// ---------------------------------------------------------------------------
// K2: exclusive scan of deg -> row_ptr[0..n]; also cursor[i] = row_ptr[i].
// ---------------------------------------------------------------------------
__global__ __launch_bounds__(1024) void k_scan(
    const int* __restrict__ deg, int* __restrict__ row_ptr,
    int* __restrict__ cursor, int n)
{
    constexpr int ELT = 40;  // 1024*40 = 40960 >= n
    __shared__ int wsum[16];
    const int tid = threadIdx.x;
    const int lane = tid & 63;
    const int wid = tid >> 6;

    int v[ELT];
    int sum = 0;
    const int base = tid * ELT;
#pragma unroll
    for (int j = 0; j < ELT; ++j) {
        int i = base + j;
        v[j] = (i < n) ? deg[i] : 0;
        sum += v[j];
    }

    int inc = sum;
#pragma unroll
    for (int off = 1; off < 64; off <<= 1) {
        int t = __shfl_up(inc, off);
        if (lane >= off) inc += t;
    }
    if (lane == 63) wsum[wid] = inc;
    __syncthreads();
    if (wid == 0) {
        int w = (lane < 16) ? wsum[lane] : 0;
        int wi = w;
#pragma unroll
        for (int off = 1; off < 16; off <<= 1) {
            int t = __shfl_up(wi, off);
            if (lane >= off) wi += t;
        }
        if (lane < 16) wsum[lane] = wi - w;
    }
    __syncthreads();

    int run = wsum[wid] + (inc - sum);
    if (tid == 0) row_ptr[0] = 0;
#pragma unroll
    for (int j = 0; j < ELT; ++j) {
        int i = base + j;
        if (i < n) {
            cursor[i] = run;
            run += v[j];
            row_ptr[i + 1] = run;
        }
    }
}

// ---------------------------------------------------------------------------
// K3: bucket edges into CSR slots: slot = atomicAdd(&cursor[dst], 1).
// ---------------------------------------------------------------------------
__global__ __launch_bounds__(256) void k_bucket(
    const int* __restrict__ ei, int E, int n,
    int* __restrict__ cursor, int* __restrict__ csr_src)
{
    int e = blockIdx.x * 256 + threadIdx.x;
    if (e >= E + n) return;
    int src, dst;
    if (e < E) { src = ei[e]; dst = ei[E + e]; }
    else       { src = dst = e - E; }
    int slot = atomicAdd(&cursor[dst], 1);
    csr_src[slot] = src;
}

// ---------------------------------------------------------------------------
// K4: per-dst gather-aggregate, bf16 messages, 4-way edge unroll for MLP.
// 64 threads/node (2 channels each), 4 nodes/block.
// ---------------------------------------------------------------------------
__global__ __launch_bounds__(256) void k_gather(
    const int* __restrict__ row_ptr, const int* __restrict__ csr_src,
    const float* __restrict__ a_s, const float* __restrict__ a_d,
    const unsigned* __restrict__ xpb, float* __restrict__ agg, int n)
{
    int node = blockIdx.x * 4 + (threadIdx.x >> 6);
    if (node >= n) return;
    int lane = threadIdx.x & 63;
    int h = lane >> 3;
    float ad = a_d[(size_t)node * 8 + h];
    int beg = row_ptr[node], end = row_ptr[node + 1];
    float acc0 = 0.f, acc1 = 0.f, s = 0.f;

    int slot = beg;
    for (; slot + 4 <= end; slot += 4) {
        int s0 = csr_src[slot + 0];
        int s1 = csr_src[slot + 1];
        int s2 = csr_src[slot + 2];
        int s3 = csr_src[slot + 3];
        float w0 = a_s[(size_t)s0 * 8 + h];
        float w1 = a_s[(size_t)s1 * 8 + h];
        float w2 = a_s[(size_t)s2 * 8 + h];
        float w3 = a_s[(size_t)s3 * 8 + h];
        unsigned u0 = xpb[(size_t)s0 * 64 + lane];
        unsigned u1 = xpb[(size_t)s1 * 64 + lane];
        unsigned u2 = xpb[(size_t)s2 * 64 + lane];
        unsigned u3 = xpb[(size_t)s3 * 64 + lane];
        float v0 = w0 + ad; v0 = v0 > 0.f ? v0 : NEG_SLOPE * v0;
        float v1 = w1 + ad; v1 = v1 > 0.f ? v1 : NEG_SLOPE * v1;
        float v2 = w2 + ad; v2 = v2 > 0.f ? v2 : NEG_SLOPE * v2;
        float v3 = w3 + ad; v3 = v3 > 0.f ? v3 : NEG_SLOPE * v3;
        float p0 = __expf(v0), p1 = __expf(v1), p2 = __expf(v2), p3 = __expf(v3);
        s += (p0 + p1) + (p2 + p3);
        acc0 = fmaf(p0, __uint_as_float(u0 << 16), acc0);
        acc1 = fmaf(p0, __uint_as_float(u0 & 0xffff0000u), acc1);
        acc0 = fmaf(p1, __uint_as_float(u1 << 16), acc0);
        acc1 = fmaf(p1, __uint_as_float(u1 & 0xffff0000u), acc1);
        acc0 = fmaf(p2, __uint_as_float(u2 << 16), acc0);
        acc1 = fmaf(p2, __uint_as_float(u2 & 0xffff0000u), acc1);
        acc0 = fmaf(p3, __uint_as_float(u3 << 16), acc0);
        acc1 = fmaf(p3, __uint_as_float(u3 & 0xffff0000u), acc1);
    }
    for (; slot < end; ++slot) {
        int src = csr_src[slot];
        float v = a_s[(size_t)src * 8 + h] + ad;
        v = v > 0.f ? v : NEG_SLOPE * v;
        float p = __expf(v);
        s += p;
        unsigned u = xpb[(size_t)src * 64 + lane];
        acc0 = fmaf(p, __uint_as_float(u << 16), acc0);
        acc1 = fmaf(p, __uint_as_float(u & 0xffff0000u), acc1);
    }
    float inv = 1.0f / (s + SM_EPS);
    *(float2*)&agg[(size_t)node * 128 + lane * 2] = make_float2(acc0 * inv, acc1 * inv);
}

// ---------------------------------------------------------------------------
// K5: per-channel sum / sum-of-squares of h = agg + bias (BN stats).
// ---------------------------------------------------------------------------
__global__ __launch_bounds__(256) void k_bnstats(
    const float* __restrict__ agg, const float* __restrict__ bias, int n,
    float* __restrict__ stats)
{
    int c = threadIdx.x & 127;
    int half = threadIdx.x >> 7;
    float b = bias[c];
    float s = 0.f, s2 = 0.f;
    for (int r = blockIdx.x * 2 + half; r < n; r += gridDim.x * 2) {
        float v = agg[(size_t)r * 128 + c] + b;
        s += v;
        s2 += v * v;
    }
    atomicAdd(&stats[c], s);
    atomicAdd(&stats[128 + c], s2);
}

// ---------------------------------------------------------------------------
// K6: finalize: BN (batch stats, biased var) + ReLU + residual.
// ---------------------------------------------------------------------------
__global__ __launch_bounds__(256) void k_final(
    const float* __restrict__ agg, const float* __restrict__ bias,
    const float* __restrict__ gamma, const float* __restrict__ beta,
    const float* __restrict__ stats, const float* __restrict__ x,
    float* __restrict__ out, int n)
{
    int i = blockIdx.x * 256 + threadIdx.x;
    int total = n * 128;
    if (i >= total) return;
    int c = i & 127;
    float invn = 1.0f / (float)n;
    float mean = stats[c] * invn;
    float var = stats[128 + c] * invn - mean * mean;
    float v = agg[i] + bias[c];
    v = (v - mean) * rsqrtf(var + BN_EPS) * gamma[c] + beta[c];
    v = fmaxf(v, 0.f);
    out[i] = v + x[i];
}

// ---------------------------------------------------------------------------
extern "C" void kernel_launch(void* const* d_in, const int* in_sizes, int n_in,
                              void* d_out, int out_size, void* d_ws, size_t ws_size,
                              hipStream_t stream)
{
    const float* x        = (const float*)d_in[0];
    const int*   ei       = (const int*)d_in[1];
    const float* W        = (const float*)d_in[2];
    const float* att_src  = (const float*)d_in[3];
    const float* att_dst  = (const float*)d_in[4];
    const float* bias     = (const float*)d_in[5];
    const float* bn_gamma = (const float*)d_in[6];
    const float* bn_beta  = (const float*)d_in[7];
    float* out = (float*)d_out;

    const int n = in_sizes[0] / 128;
    const int E = in_sizes[1] / 2;
    const int tot = E + n;

    // workspace layout: stats and deg adjacent for a single memset
    float*    stats   = (float*)d_ws;                   // 256
    int*      deg     = (int*)(stats + 256);            // n
    int*      row_ptr = deg + n;                        // n+1
    int*      cursor  = row_ptr + n + 1;                // n
    int*      csr_src = cursor + n;                     // E+n
    unsigned* xpb     = (unsigned*)(csr_src + tot);     // n*64 (bf16 x2)
    float*    agg     = (float*)(xpb + (size_t)n * 64); // n*128
    float*    a_s     = agg + (size_t)n * 128;          // n*8
    float*    a_d     = a_s + (size_t)n * 8;            // n*8

    hipMemsetAsync(stats, 0, (256 + (size_t)n) * sizeof(int), stream);

    k_gemm<<<(n + 31) / 32, 256, 0, stream>>>(x, W, att_src, att_dst, ei, E,
                                              xpb, a_s, a_d, deg, n);
    k_scan<<<1, 1024, 0, stream>>>(deg, row_ptr, cursor, n);
    k_bucket<<<(tot + 255) / 256, 256, 0, stream>>>(ei, E, n, cursor, csr_src);
    k_gather<<<(n + 3) / 4, 256, 0, stream>>>(row_ptr, csr_src, a_s, a_d, xpb, agg, n);
    k_bnstats<<<320, 256, 0, stream>>>(agg, bias, n, stats);
    k_final<<<(n * 128 + 255) / 256, 256, 0, stream>>>(agg, bias, bn_gamma, bn_beta,
                                                       stats, x, out, n);
}

// Round 5
// 259.868 us; speedup vs baseline: 6.0210x; 1.2075x over previous
//
#include <hip/hip_runtime.h>
#include <math.h>

// GAT layer, R5: multi-block scan (fixes 64us spilled single-block scan),
// 8-way unrolled gather. Pipeline: memset -> gemm(+count) -> part -> apply
// (scan) -> bucket -> gather -> bnstats -> final.

constexpr float NEG_SLOPE = 0.2f;
constexpr float BN_EPS = 1e-5f;
constexpr float SM_EPS = 1e-16f;

__device__ inline unsigned bf16rne(float f) {
    unsigned b = __float_as_uint(f);
    return (b + 0x7fffu + ((b >> 16) & 1u)) >> 16;
}

// ---------------------------------------------------------------------------
// K1: degree histogram (grid-stride) + xp = x@W -> bf16 + attention dots.
// ---------------------------------------------------------------------------
__global__ __launch_bounds__(256) void k_gemm(
    const float* __restrict__ x, const float* __restrict__ W,
    const float* __restrict__ att_src, const float* __restrict__ att_dst,
    const int* __restrict__ ei, int E,
    unsigned* __restrict__ xpb, float* __restrict__ a_s, float* __restrict__ a_d,
    int* __restrict__ deg, int n)
{
    {
        int tot = E + n;
        int stride = gridDim.x * 256;
        for (int e = blockIdx.x * 256 + threadIdx.x; e < tot; e += stride) {
            int dst = (e < E) ? ei[E + e] : (e - E);
            atomicAdd(&deg[dst], 1);
        }
    }

    __shared__ float Xl[32 * 128];
    const int tid = threadIdx.x;
    const int row0 = blockIdx.x * 32;

    const float4* x4 = (const float4*)x;
    float4* Xl4 = (float4*)Xl;
#pragma unroll
    for (int i = 0; i < 4; ++i) {
        int idx = tid + i * 256;
        int r = row0 + (idx >> 5);
        Xl4[idx] = (r < n) ? x4[(size_t)r * 32 + (idx & 31)]
                           : make_float4(0.f, 0.f, 0.f, 0.f);
    }
    __syncthreads();

    const int tx = tid & 31;
    const int ty = tid >> 5;

    float acc[4][4] = {};
    for (int k = 0; k < 128; k += 4) {
        float4 xv[4];
#pragma unroll
        for (int r = 0; r < 4; ++r)
            xv[r] = *(const float4*)&Xl[(ty * 4 + r) * 128 + k];
#pragma unroll
        for (int kk = 0; kk < 4; ++kk) {
            float4 wv = *(const float4*)&W[(size_t)(k + kk) * 128 + tx * 4];
#pragma unroll
            for (int r = 0; r < 4; ++r) {
                float xs = (&xv[r].x)[kk];
                acc[r][0] = fmaf(xs, wv.x, acc[r][0]);
                acc[r][1] = fmaf(xs, wv.y, acc[r][1]);
                acc[r][2] = fmaf(xs, wv.z, acc[r][2]);
                acc[r][3] = fmaf(xs, wv.w, acc[r][3]);
            }
        }
    }

#pragma unroll
    for (int r = 0; r < 4; ++r) {
        int row = row0 + ty * 4 + r;
        if (row < n) {
            uint2 u;
            u.x = bf16rne(acc[r][0]) | (bf16rne(acc[r][1]) << 16);
            u.y = bf16rne(acc[r][2]) | (bf16rne(acc[r][3]) << 16);
            *(uint2*)&xpb[(size_t)row * 64 + tx * 2] = u;
        }
    }

    const int h = tx >> 2;
    const int fbase = (tx & 3) * 4;
    float asv[4], adv[4];
#pragma unroll
    for (int j = 0; j < 4; ++j) {
        asv[j] = att_src[h * 16 + fbase + j];
        adv[j] = att_dst[h * 16 + fbase + j];
    }
#pragma unroll
    for (int r = 0; r < 4; ++r) {
        float ps = acc[r][0] * asv[0] + acc[r][1] * asv[1] +
                   acc[r][2] * asv[2] + acc[r][3] * asv[3];
        float pd = acc[r][0] * adv[0] + acc[r][1] * adv[1] +
                   acc[r][2] * adv[2] + acc[r][3] * adv[3];
        ps += __shfl_xor(ps, 1); ps += __shfl_xor(ps, 2);
        pd += __shfl_xor(pd, 1); pd += __shfl_xor(pd, 2);
        if ((tx & 3) == 0) {
            int row = row0 + ty * 4 + r;
            if (row < n) {
                a_s[(size_t)row * 8 + h] = ps;
                a_d[(size_t)row * 8 + h] = pd;
            }
        }
    }
}

// ---------------------------------------------------------------------------
// K2a: per-block partial sums of deg (256 elems/block).
// ---------------------------------------------------------------------------
__global__ __launch_bounds__(256) void k_part(
    const int* __restrict__ deg, int* __restrict__ partial, int n)
{
    __shared__ int wsum[4];
    int tid = threadIdx.x;
    int i = blockIdx.x * 256 + tid;
    int v = (i < n) ? deg[i] : 0;
#pragma unroll
    for (int off = 32; off > 0; off >>= 1) v += __shfl_down(v, off);
    if ((tid & 63) == 0) wsum[tid >> 6] = v;
    __syncthreads();
    if (tid == 0) partial[blockIdx.x] = wsum[0] + wsum[1] + wsum[2] + wsum[3];
}

// ---------------------------------------------------------------------------
// K2b: block b: redundant wave-scan of partials -> block offset; block-scan
// of its 256 deg values; write row_ptr[i+1] and cursor[i] (=row_ptr[i]).
// ---------------------------------------------------------------------------
__global__ __launch_bounds__(256) void k_apply(
    const int* __restrict__ deg, const int* __restrict__ partial, int nb,
    int* __restrict__ row_ptr, int* __restrict__ cursor, int n)
{
    __shared__ int s_off;
    __shared__ int woff[4];
    const int tid = threadIdx.x;
    const int lane = tid & 63;
    const int wid = tid >> 6;

    // wave 0: exclusive prefix of partial[] up to blockIdx.x
    if (wid == 0) {
        int carry = 0;
        int nseg = (nb + 63) / 64;
        for (int seg = 0; seg < nseg; ++seg) {
            int idx = seg * 64 + lane;
            int v = (idx < nb) ? partial[idx] : 0;
            int inc = v;
#pragma unroll
            for (int off = 1; off < 64; off <<= 1) {
                int t = __shfl_up(inc, off);
                if (lane >= off) inc += t;
            }
            if (idx == blockIdx.x) s_off = carry + inc - v;
            carry += __shfl(inc, 63);
        }
    }
    __syncthreads();

    int i = blockIdx.x * 256 + tid;
    int v = (i < n) ? deg[i] : 0;
    int inc = v;
#pragma unroll
    for (int off = 1; off < 64; off <<= 1) {
        int t = __shfl_up(inc, off);
        if (lane >= off) inc += t;
    }
    if (lane == 63) woff[wid] = inc;
    __syncthreads();
    if (tid == 0) {
        int a = 0;
#pragma unroll
        for (int w = 0; w < 4; ++w) { int t = woff[w]; woff[w] = a; a += t; }
    }
    __syncthreads();

    int excl = s_off + woff[wid] + inc - v;
    if (i < n) {
        cursor[i] = excl;
        row_ptr[i + 1] = excl + v;
    }
    if (i == 0) row_ptr[0] = 0;
}

// ---------------------------------------------------------------------------
// K3: bucket edges into CSR slots: slot = atomicAdd(&cursor[dst], 1).
// ---------------------------------------------------------------------------
__global__ __launch_bounds__(256) void k_bucket(
    const int* __restrict__ ei, int E, int n,
    int* __restrict__ cursor, int* __restrict__ csr_src)
{
    int e = blockIdx.x * 256 + threadIdx.x;
    if (e >= E + n) return;
    int src, dst;
    if (e < E) { src = ei[e]; dst = ei[E + e]; }
    else       { src = dst = e - E; }
    int slot = atomicAdd(&cursor[dst], 1);
    csr_src[slot] = src;
}

// ---------------------------------------------------------------------------
// K4: per-dst gather-aggregate, bf16 messages, 8-way edge unroll (MLP).
// 64 threads/node (2 channels each), 4 nodes/block.
// ---------------------------------------------------------------------------
__global__ __launch_bounds__(256) void k_gather(
    const int* __restrict__ row_ptr, const int* __restrict__ csr_src,
    const float* __restrict__ a_s, const float* __restrict__ a_d,
    const unsigned* __restrict__ xpb, float* __restrict__ agg, int n)
{
    int node = blockIdx.x * 4 + (threadIdx.x >> 6);
    if (node >= n) return;
    int lane = threadIdx.x & 63;
    int h = lane >> 3;
    float ad = a_d[(size_t)node * 8 + h];
    int beg = row_ptr[node], end = row_ptr[node + 1];
    float acc0 = 0.f, acc1 = 0.f, s = 0.f;

    int slot = beg;
    for (; slot + 8 <= end; slot += 8) {
        int sx[8]; float w[8]; unsigned u[8];
#pragma unroll
        for (int j = 0; j < 8; ++j) sx[j] = csr_src[slot + j];
#pragma unroll
        for (int j = 0; j < 8; ++j) w[j] = a_s[(size_t)sx[j] * 8 + h];
#pragma unroll
        for (int j = 0; j < 8; ++j) u[j] = xpb[(size_t)sx[j] * 64 + lane];
#pragma unroll
        for (int j = 0; j < 8; ++j) {
            float v = w[j] + ad;
            v = v > 0.f ? v : NEG_SLOPE * v;
            float p = __expf(v);
            s += p;
            acc0 = fmaf(p, __uint_as_float(u[j] << 16), acc0);
            acc1 = fmaf(p, __uint_as_float(u[j] & 0xffff0000u), acc1);
        }
    }
    for (; slot < end; ++slot) {
        int src = csr_src[slot];
        float v = a_s[(size_t)src * 8 + h] + ad;
        v = v > 0.f ? v : NEG_SLOPE * v;
        float p = __expf(v);
        s += p;
        unsigned u = xpb[(size_t)src * 64 + lane];
        acc0 = fmaf(p, __uint_as_float(u << 16), acc0);
        acc1 = fmaf(p, __uint_as_float(u & 0xffff0000u), acc1);
    }
    float inv = 1.0f / (s + SM_EPS);
    *(float2*)&agg[(size_t)node * 128 + lane * 2] = make_float2(acc0 * inv, acc1 * inv);
}

// ---------------------------------------------------------------------------
// K5: per-channel sum / sum-of-squares of h = agg + bias (BN stats).
// ---------------------------------------------------------------------------
__global__ __launch_bounds__(256) void k_bnstats(
    const float* __restrict__ agg, const float* __restrict__ bias, int n,
    float* __restrict__ stats)
{
    int c = threadIdx.x & 127;
    int half = threadIdx.x >> 7;
    float b = bias[c];
    float s = 0.f, s2 = 0.f;
    for (int r = blockIdx.x * 2 + half; r < n; r += gridDim.x * 2) {
        float v = agg[(size_t)r * 128 + c] + b;
        s += v;
        s2 += v * v;
    }
    atomicAdd(&stats[c], s);
    atomicAdd(&stats[128 + c], s2);
}

// ---------------------------------------------------------------------------
// K6: finalize: BN (batch stats, biased var) + ReLU + residual.
// ---------------------------------------------------------------------------
__global__ __launch_bounds__(256) void k_final(
    const float* __restrict__ agg, const float* __restrict__ bias,
    const float* __restrict__ gamma, const float* __restrict__ beta,
    const float* __restrict__ stats, const float* __restrict__ x,
    float* __restrict__ out, int n)
{
    int i = blockIdx.x * 256 + threadIdx.x;
    int total = n * 128;
    if (i >= total) return;
    int c = i & 127;
    float invn = 1.0f / (float)n;
    float mean = stats[c] * invn;
    float var = stats[128 + c] * invn - mean * mean;
    float v = agg[i] + bias[c];
    v = (v - mean) * rsqrtf(var + BN_EPS) * gamma[c] + beta[c];
    v = fmaxf(v, 0.f);
    out[i] = v + x[i];
}

// ---------------------------------------------------------------------------
extern "C" void kernel_launch(void* const* d_in, const int* in_sizes, int n_in,
                              void* d_out, int out_size, void* d_ws, size_t ws_size,
                              hipStream_t stream)
{
    const float* x        = (const float*)d_in[0];
    const int*   ei       = (const int*)d_in[1];
    const float* W        = (const float*)d_in[2];
    const float* att_src  = (const float*)d_in[3];
    const float* att_dst  = (const float*)d_in[4];
    const float* bias     = (const float*)d_in[5];
    const float* bn_gamma = (const float*)d_in[6];
    const float* bn_beta  = (const float*)d_in[7];
    float* out = (float*)d_out;

    const int n = in_sizes[0] / 128;
    const int E = in_sizes[1] / 2;
    const int tot = E + n;
    const int nb = (n + 255) / 256;

    // workspace layout: stats and deg adjacent for a single memset
    float*    stats   = (float*)d_ws;                   // 256
    int*      deg     = (int*)(stats + 256);            // n
    int*      row_ptr = deg + n;                        // n+1
    int*      cursor  = row_ptr + n + 1;                // n
    int*      partial = cursor + n;                     // nb
    int*      csr_src = partial + nb;                   // E+n
    unsigned* xpb     = (unsigned*)(csr_src + tot);     // n*64 (bf16 x2)
    float*    agg     = (float*)(xpb + (size_t)n * 64); // n*128
    float*    a_s     = agg + (size_t)n * 128;          // n*8
    float*    a_d     = a_s + (size_t)n * 8;            // n*8

    hipMemsetAsync(stats, 0, (256 + (size_t)n) * sizeof(int), stream);

    k_gemm<<<(n + 31) / 32, 256, 0, stream>>>(x, W, att_src, att_dst, ei, E,
                                              xpb, a_s, a_d, deg, n);
    k_part<<<nb, 256, 0, stream>>>(deg, partial, n);
    k_apply<<<nb, 256, 0, stream>>>(deg, partial, nb, row_ptr, cursor, n);
    k_bucket<<<(tot + 255) / 256, 256, 0, stream>>>(ei, E, n, cursor, csr_src);
    k_gather<<<(n + 3) / 4, 256, 0, stream>>>(row_ptr, csr_src, a_s, a_d, xpb, agg, n);
    k_bnstats<<<320, 256, 0, stream>>>(agg, bias, n, stats);
    k_final<<<(n * 128 + 255) / 256, 256, 0, stream>>>(agg, bias, bn_gamma, bn_beta,
                                                       stats, x, out, n);
}

// Round 7
// 253.802 us; speedup vs baseline: 6.1649x; 1.0239x over previous
//
#include <hip/hip_runtime.h>
#include <math.h>

// GAT layer, R7: MFMA bf16 GEMM — fixes R6's Ws staging OOB (16 uint4/row,
// not 8). Pipeline: memset -> wconv -> gemm(+count) -> part -> apply ->
// bucket -> gather -> bnstats -> final.

constexpr float NEG_SLOPE = 0.2f;
constexpr float BN_EPS = 1e-5f;
constexpr float SM_EPS = 1e-16f;

typedef __attribute__((ext_vector_type(8))) short short8;   // 8 bf16 = 4 VGPRs
typedef __attribute__((ext_vector_type(4))) float f32x4;    // MFMA acc

__device__ inline unsigned bf16rne(float f) {
    unsigned b = __float_as_uint(f);
    return (b + 0x7fffu + ((b >> 16) & 1u)) >> 16;
}

// ---------------------------------------------------------------------------
// K0: W [k][n] fp32 -> Wt [n][k] bf16 (for contiguous B-fragment loads).
// ---------------------------------------------------------------------------
__global__ __launch_bounds__(256) void k_wconv(
    const float* __restrict__ W, unsigned short* __restrict__ Wtg)
{
    int idx = blockIdx.x * 256 + threadIdx.x;   // 16384 total
    if (idx >= 128 * 128) return;
    int k = idx >> 7, nc = idx & 127;
    Wtg[nc * 128 + k] = (unsigned short)bf16rne(W[idx]);
}

// ---------------------------------------------------------------------------
// K1: degree histogram (grid-stride) + xp = x@W via MFMA bf16 + att dots.
// 64 rows/block, 4 waves; each wave: 16-row stripe x 128 cols.
// LDS rows padded +8 bf16 (136) so b128 frag reads stay 2-way (free).
// ---------------------------------------------------------------------------
__global__ __launch_bounds__(256) void k_gemm(
    const float* __restrict__ x, const unsigned short* __restrict__ Wtg,
    const float* __restrict__ att_src, const float* __restrict__ att_dst,
    const int* __restrict__ ei, int E,
    unsigned* __restrict__ xpb, float* __restrict__ a_s, float* __restrict__ a_d,
    int* __restrict__ deg, int n)
{
    // fused degree count over E+n edges (self-loops are [E, E+n))
    {
        int tot = E + n;
        int stride = gridDim.x * 256;
        for (int e = blockIdx.x * 256 + threadIdx.x; e < tot; e += stride) {
            int dst = (e < E) ? ei[E + e] : (e - E);
            atomicAdd(&deg[dst], 1);
        }
    }

    __shared__ __align__(16) unsigned short Xs[64 * 136];   // 17408 B
    __shared__ __align__(16) unsigned short Ws[128 * 136];  // 34816 B

    const int tid = threadIdx.x;
    const int row0 = blockIdx.x * 64;

    // stage x rows -> bf16 LDS (8 float4 per thread)
    const float4* x4 = (const float4*)x;
#pragma unroll
    for (int i = 0; i < 8; ++i) {
        int idx = tid + i * 256;          // 2048 float4: 64 rows x 32
        int r = idx >> 5, c4 = idx & 31;
        float4 v = (row0 + r < n) ? x4[(size_t)(row0 + r) * 32 + c4]
                                  : make_float4(0.f, 0.f, 0.f, 0.f);
        uint2 u;
        u.x = bf16rne(v.x) | (bf16rne(v.y) << 16);
        u.y = bf16rne(v.z) | (bf16rne(v.w) << 16);
        *(uint2*)&Xs[r * 136 + c4 * 4] = u;
    }
    // stage Wt -> LDS: 128 rows x 16 uint4 per row (128 bf16 = 256 B)
    const uint4* w4 = (const uint4*)Wtg;
#pragma unroll
    for (int i = 0; i < 8; ++i) {
        int idx = tid + i * 256;          // 2048 uint4 total
        int r = idx >> 4, c = idx & 15;
        *(uint4*)&Ws[r * 136 + c * 8] = w4[idx];
    }
    __syncthreads();

    const int lane = tid & 63;
    const int wid = tid >> 6;
    const int quad = lane >> 4;
    const int l16 = lane & 15;

    // A fragments: A[m=l16][k=quad*8+j] per 32-wide k-tile
    short8 afrag[4];
#pragma unroll
    for (int kt = 0; kt < 4; ++kt)
        afrag[kt] = *(const short8*)&Xs[(wid * 16 + l16) * 136 + kt * 32 + quad * 8];

    f32x4 acc[8];
#pragma unroll
    for (int ct = 0; ct < 8; ++ct) acc[ct] = (f32x4){0.f, 0.f, 0.f, 0.f};

#pragma unroll
    for (int ct = 0; ct < 8; ++ct) {
#pragma unroll
        for (int kt = 0; kt < 4; ++kt) {
            short8 b = *(const short8*)&Ws[(ct * 16 + l16) * 136 + kt * 32 + quad * 8];
            acc[ct] = __builtin_amdgcn_mfma_f32_16x16x32_bf16(afrag[kt], b, acc[ct], 0, 0, 0);
        }
    }

    // epilogue: C layout col = l16 (within ct tile), row = quad*4 + r.
    // ct tile == head h (16 cols per head).
    float att_s[8], att_d[8];
#pragma unroll
    for (int ct = 0; ct < 8; ++ct) {
        att_s[ct] = att_src[ct * 16 + l16];
        att_d[ct] = att_dst[ct * 16 + l16];
    }
    const int rowbase = row0 + wid * 16 + quad * 4;
#pragma unroll
    for (int ct = 0; ct < 8; ++ct) {
#pragma unroll
        for (int r = 0; r < 4; ++r) {
            float val = acc[ct][r];
            int row = rowbase + r;
            // pack col pairs -> bf16x2, even lanes write
            float other = __shfl_xor(val, 1);
            if (!(lane & 1) && row < n) {
                unsigned u = bf16rne(val) | (bf16rne(other) << 16);
                xpb[(size_t)row * 64 + ct * 8 + (l16 >> 1)] = u;
            }
            // attention dots: reduce over f = l16 within each 16-lane group
            float ps = val * att_s[ct];
            float pd = val * att_d[ct];
            ps += __shfl_xor(ps, 1); ps += __shfl_xor(ps, 2);
            ps += __shfl_xor(ps, 4); ps += __shfl_xor(ps, 8);
            pd += __shfl_xor(pd, 1); pd += __shfl_xor(pd, 2);
            pd += __shfl_xor(pd, 4); pd += __shfl_xor(pd, 8);
            if (l16 == 0 && row < n) {
                a_s[(size_t)row * 8 + ct] = ps;
                a_d[(size_t)row * 8 + ct] = pd;
            }
        }
    }
}

// ---------------------------------------------------------------------------
// K2a: per-block partial sums of deg (256 elems/block).
// ---------------------------------------------------------------------------
__global__ __launch_bounds__(256) void k_part(
    const int* __restrict__ deg, int* __restrict__ partial, int n)
{
    __shared__ int wsum[4];
    int tid = threadIdx.x;
    int i = blockIdx.x * 256 + tid;
    int v = (i < n) ? deg[i] : 0;
#pragma unroll
    for (int off = 32; off > 0; off >>= 1) v += __shfl_down(v, off);
    if ((tid & 63) == 0) wsum[tid >> 6] = v;
    __syncthreads();
    if (tid == 0) partial[blockIdx.x] = wsum[0] + wsum[1] + wsum[2] + wsum[3];
}

// ---------------------------------------------------------------------------
// K2b: block offset via redundant wave-scan of partials; block-scan chunk;
// write row_ptr[i+1] and cursor[i] (=row_ptr[i]).
// ---------------------------------------------------------------------------
__global__ __launch_bounds__(256) void k_apply(
    const int* __restrict__ deg, const int* __restrict__ partial, int nb,
    int* __restrict__ row_ptr, int* __restrict__ cursor, int n)
{
    __shared__ int s_off;
    __shared__ int woff[4];
    const int tid = threadIdx.x;
    const int lane = tid & 63;
    const int wid = tid >> 6;

    if (wid == 0) {
        int carry = 0;
        int nseg = (nb + 63) / 64;
        for (int seg = 0; seg < nseg; ++seg) {
            int idx = seg * 64 + lane;
            int v = (idx < nb) ? partial[idx] : 0;
            int inc = v;
#pragma unroll
            for (int off = 1; off < 64; off <<= 1) {
                int t = __shfl_up(inc, off);
                if (lane >= off) inc += t;
            }
            if (idx == blockIdx.x) s_off = carry + inc - v;
            carry += __shfl(inc, 63);
        }
    }
    __syncthreads();

    int i = blockIdx.x * 256 + tid;
    int v = (i < n) ? deg[i] : 0;
    int inc = v;
#pragma unroll
    for (int off = 1; off < 64; off <<= 1) {
        int t = __shfl_up(inc, off);
        if (lane >= off) inc += t;
    }
    if (lane == 63) woff[wid] = inc;
    __syncthreads();
    if (tid == 0) {
        int a = 0;
#pragma unroll
        for (int w = 0; w < 4; ++w) { int t = woff[w]; woff[w] = a; a += t; }
    }
    __syncthreads();

    int excl = s_off + woff[wid] + inc - v;
    if (i < n) {
        cursor[i] = excl;
        row_ptr[i + 1] = excl + v;
    }
    if (i == 0) row_ptr[0] = 0;
}

// ---------------------------------------------------------------------------
// K3: bucket edges into CSR slots: slot = atomicAdd(&cursor[dst], 1).
// ---------------------------------------------------------------------------
__global__ __launch_bounds__(256) void k_bucket(
    const int* __restrict__ ei, int E, int n,
    int* __restrict__ cursor, int* __restrict__ csr_src)
{
    int e = blockIdx.x * 256 + threadIdx.x;
    if (e >= E + n) return;
    int src, dst;
    if (e < E) { src = ei[e]; dst = ei[E + e]; }
    else       { src = dst = e - E; }
    int slot = atomicAdd(&cursor[dst], 1);
    csr_src[slot] = src;
}

// ---------------------------------------------------------------------------
// K4: per-dst gather-aggregate, bf16 messages, 8-way edge unroll (MLP).
// ---------------------------------------------------------------------------
__global__ __launch_bounds__(256) void k_gather(
    const int* __restrict__ row_ptr, const int* __restrict__ csr_src,
    const float* __restrict__ a_s, const float* __restrict__ a_d,
    const unsigned* __restrict__ xpb, float* __restrict__ agg, int n)
{
    int node = blockIdx.x * 4 + (threadIdx.x >> 6);
    if (node >= n) return;
    int lane = threadIdx.x & 63;
    int h = lane >> 3;
    float ad = a_d[(size_t)node * 8 + h];
    int beg = row_ptr[node], end = row_ptr[node + 1];
    float acc0 = 0.f, acc1 = 0.f, s = 0.f;

    int slot = beg;
    for (; slot + 8 <= end; slot += 8) {
        int sx[8]; float w[8]; unsigned u[8];
#pragma unroll
        for (int j = 0; j < 8; ++j) sx[j] = csr_src[slot + j];
#pragma unroll
        for (int j = 0; j < 8; ++j) w[j] = a_s[(size_t)sx[j] * 8 + h];
#pragma unroll
        for (int j = 0; j < 8; ++j) u[j] = xpb[(size_t)sx[j] * 64 + lane];
#pragma unroll
        for (int j = 0; j < 8; ++j) {
            float v = w[j] + ad;
            v = v > 0.f ? v : NEG_SLOPE * v;
            float p = __expf(v);
            s += p;
            acc0 = fmaf(p, __uint_as_float(u[j] << 16), acc0);
            acc1 = fmaf(p, __uint_as_float(u[j] & 0xffff0000u), acc1);
        }
    }
    for (; slot < end; ++slot) {
        int src = csr_src[slot];
        float v = a_s[(size_t)src * 8 + h] + ad;
        v = v > 0.f ? v : NEG_SLOPE * v;
        float p = __expf(v);
        s += p;
        unsigned u = xpb[(size_t)src * 64 + lane];
        acc0 = fmaf(p, __uint_as_float(u << 16), acc0);
        acc1 = fmaf(p, __uint_as_float(u & 0xffff0000u), acc1);
    }
    float inv = 1.0f / (s + SM_EPS);
    *(float2*)&agg[(size_t)node * 128 + lane * 2] = make_float2(acc0 * inv, acc1 * inv);
}

// ---------------------------------------------------------------------------
// K5: per-channel sum / sum-of-squares of h = agg + bias (BN stats).
// ---------------------------------------------------------------------------
__global__ __launch_bounds__(256) void k_bnstats(
    const float* __restrict__ agg, const float* __restrict__ bias, int n,
    float* __restrict__ stats)
{
    int c = threadIdx.x & 127;
    int half = threadIdx.x >> 7;
    float b = bias[c];
    float s = 0.f, s2 = 0.f;
    for (int r = blockIdx.x * 2 + half; r < n; r += gridDim.x * 2) {
        float v = agg[(size_t)r * 128 + c] + b;
        s += v;
        s2 += v * v;
    }
    atomicAdd(&stats[c], s);
    atomicAdd(&stats[128 + c], s2);
}

// ---------------------------------------------------------------------------
// K6: finalize: BN (batch stats, biased var) + ReLU + residual.
// ---------------------------------------------------------------------------
__global__ __launch_bounds__(256) void k_final(
    const float* __restrict__ agg, const float* __restrict__ bias,
    const float* __restrict__ gamma, const float* __restrict__ beta,
    const float* __restrict__ stats, const float* __restrict__ x,
    float* __restrict__ out, int n)
{
    int i = blockIdx.x * 256 + threadIdx.x;
    int total = n * 128;
    if (i >= total) return;
    int c = i & 127;
    float invn = 1.0f / (float)n;
    float mean = stats[c] * invn;
    float var = stats[128 + c] * invn - mean * mean;
    float v = agg[i] + bias[c];
    v = (v - mean) * rsqrtf(var + BN_EPS) * gamma[c] + beta[c];
    v = fmaxf(v, 0.f);
    out[i] = v + x[i];
}

// ---------------------------------------------------------------------------
extern "C" void kernel_launch(void* const* d_in, const int* in_sizes, int n_in,
                              void* d_out, int out_size, void* d_ws, size_t ws_size,
                              hipStream_t stream)
{
    const float* x        = (const float*)d_in[0];
    const int*   ei       = (const int*)d_in[1];
    const float* W        = (const float*)d_in[2];
    const float* att_src  = (const float*)d_in[3];
    const float* att_dst  = (const float*)d_in[4];
    const float* bias     = (const float*)d_in[5];
    const float* bn_gamma = (const float*)d_in[6];
    const float* bn_beta  = (const float*)d_in[7];
    float* out = (float*)d_out;

    const int n = in_sizes[0] / 128;
    const int E = in_sizes[1] / 2;
    const int tot = E + n;
    const int nb = (n + 255) / 256;

    // workspace layout: stats and deg adjacent for a single memset
    float*          stats   = (float*)d_ws;                   // 256
    int*            deg     = (int*)(stats + 256);            // n
    int*            row_ptr = deg + n;                        // n+1
    int*            cursor  = row_ptr + n + 1;                // n
    int*            partial = cursor + n;                     // nb
    int*            csr_src = partial + nb;                   // E+n
    unsigned short* Wtg     = (unsigned short*)(csr_src + tot); // 16384
    unsigned*       xpb     = (unsigned*)(Wtg + 16384);       // n*64 (bf16 x2)
    float*          agg     = (float*)(xpb + (size_t)n * 64); // n*128
    float*          a_s     = agg + (size_t)n * 128;          // n*8
    float*          a_d     = a_s + (size_t)n * 8;            // n*8

    hipMemsetAsync(stats, 0, (256 + (size_t)n) * sizeof(int), stream);

    k_wconv<<<64, 256, 0, stream>>>(W, Wtg);
    k_gemm<<<(n + 63) / 64, 256, 0, stream>>>(x, Wtg, att_src, att_dst, ei, E,
                                              xpb, a_s, a_d, deg, n);
    k_part<<<nb, 256, 0, stream>>>(deg, partial, n);
    k_apply<<<nb, 256, 0, stream>>>(deg, partial, nb, row_ptr, cursor, n);
    k_bucket<<<(tot + 255) / 256, 256, 0, stream>>>(ei, E, n, cursor, csr_src);
    k_gather<<<(n + 3) / 4, 256, 0, stream>>>(row_ptr, csr_src, a_s, a_d, xpb, agg, n);
    k_bnstats<<<320, 256, 0, stream>>>(agg, bias, n, stats);
    k_final<<<(n * 128 + 255) / 256, 256, 0, stream>>>(agg, bias, bn_gamma, bn_beta,
                                                       stats, x, out, n);
}